// Round 4
// baseline (212.831 us; speedup 1.0000x reference)
//
#include <hip/hip_runtime.h>

#define NT 8
#define NY 32
#define NX 32
#define NN 1024  // NY*NX

typedef __attribute__((ext_vector_type(4))) float f32x4;

// Stencil coefficients of M = I + A for one node. c[(ry+1)*3+(rx+1)] is the
// coefficient toward target offset (ry,rx); zeroed when the TARGET node falls
// off-grid (matches reference `valid` masking on the column node).
__device__ __forceinline__ void node_coefs(const float* __restrict__ kap,
                                           const float* __restrict__ m,
                                           const float* __restrict__ H,
                                           const float* __restrict__ tau,
                                           int b, int node, int tc,
                                           int iy, int ix,
                                           float* c /*[9]*/, float& w) {
    const int base = node * NT + tc;                 // [.., node, t] layout, last dim NT
    const float kp  = kap[(b * NN) * NT + base];
    const float m1  = m[((b * 2 + 0) * NN) * NT + base];
    const float m2  = m[((b * 2 + 1) * NN) * NT + base];
    const float h11 = H[((b * 4 + 0) * NN) * NT + base];
    const float h12 = H[((b * 4 + 1) * NN) * NT + base];
    const float h22 = H[((b * 4 + 3) * NN) * NT + base];
    const float tv  = tau[(b * NN) * NT + base];
    w = 1.0f / (tv * tv);

    const float cxy = 0.5f * h12;
    const bool ym = iy > 0, yp = iy < NY - 1;
    const bool xm = ix > 0, xp = ix < NX - 1;

    c[4] = 1.0f + kp * kp + 2.0f * h11 + 2.0f * h22;
    c[0] = (ym && xm) ? -cxy               : 0.0f;
    c[1] =  ym        ? (-h22 - 0.5f * m2) : 0.0f;
    c[2] = (ym && xp) ?  cxy               : 0.0f;
    c[3] =  xm        ? (-h11 - 0.5f * m1) : 0.0f;
    c[5] =  xp        ? (-h11 + 0.5f * m1) : 0.0f;
    c[6] = (yp && xm) ?  cxy               : 0.0f;
    c[7] =  yp        ? (-h22 + 0.5f * m2) : 0.0f;
    c[8] = (yp && xp) ? -cxy               : 0.0f;
}

__device__ __forceinline__ void nt_store(f32x4* p, const float4& v) {
    __builtin_nontemporal_store(*(const f32x4*)&v, p);
}

// Fused kernel, 16 j's per block (half a grid row at one (b,t)).
// Phase 0: stencil coefs for the 3x18 neighborhood nodes (54 nodes).
// Phase 1: the 688 nonzero values (16 j x (25 D + 9 L + 9 U)).
// Phase 2: stream out 48 NONTEMPORAL float4 stores per thread (192 KB/block).
// nt stores bypass the write-allocate fetch (vendor fill: 805 MB written,
// 14.5 KB fetched) -- ordinary stores were paying 2x HBM traffic.
__global__ __launch_bounds__(256) void spde_fused(const float* __restrict__ kap,
                                                  const float* __restrict__ m,
                                                  const float* __restrict__ H,
                                                  const float* __restrict__ tau,
                                                  float* __restrict__ out) {
    __shared__ float sc[3][18][9];   // coefs of node (jy-1+ly, jx0-1+lx)
    __shared__ float sw[3][18];      // w_t at those nodes (0 off-grid)
    __shared__ float valsD[16][25];
    __shared__ float valsL[16][9];
    __shared__ float valsU[16][9];

    const int gb   = blockIdx.x;         // b*512 + t*64 + jy*2 + half
    const int half = gb & 1;
    const int jy   = (gb >> 1) & 31;
    const int t    = (gb >> 6) & 7;
    const int b    = gb >> 9;
    const int jx0  = half * 16;
    const int tid  = threadIdx.x;

    if (tid < 54) {   // phase 0
        const int ly = tid / 18, lx = tid % 18;
        const int iy = jy + ly - 1, ix = jx0 + lx - 1;
        float c[9];
        float w = 0.0f;
        if (iy >= 0 && iy < NY && ix >= 0 && ix < NX) {
            node_coefs(kap, m, H, tau, b, iy * NX + ix, t, iy, ix, c, w);
        } else {
            #pragma unroll
            for (int q = 0; q < 9; ++q) c[q] = 0.0f;
        }
        #pragma unroll
        for (int q = 0; q < 9; ++q) sc[ly][lx][q] = c[q];
        sw[ly][lx] = w;
    }
    __syncthreads();

    // phase 1: 688 values over 256 threads (<=3 each)
    #pragma unroll
    for (int pass = 0; pass < 3; ++pass) {
        const int e = tid + pass * 256;
        if (e < 400) {                       // D: sum_i w[i] M[i,j] M[i,k]
            const int jj = e / 25, l = e % 25;
            const int dy = l / 5 - 2, dx = l % 5 - 2;
            float acc = 0.0f;
            #pragma unroll
            for (int d = 0; d < 9; ++d) {    // rows i = j + off_d
                const int ey = d / 3 - 1, ex = d % 3 - 1;
                const int r2y = dy - ey, r2x = dx - ex;
                if (r2y >= -1 && r2y <= 1 && r2x >= -1 && r2x <= 1) {
                    const float* ci = sc[ey + 1][jj + 1 + ex];
                    acc += sw[ey + 1][jj + 1 + ex] * ci[8 - d]
                                                   * ci[(r2y + 1) * 3 + (r2x + 1)];
                }
            }
            if (l == 12 && t < NT - 1) {     // diagonal: + w_{t+1}[j]
                const int j = jy * NX + jx0 + jj;
                const float tv = tau[((size_t)b * NN + j) * NT + (t + 1)];
                acc += 1.0f / (tv * tv);
            }
            valsD[jj][l] = acc;
        } else if (e < 544) {                // L: -w_t[k] M_t[k,j], k=j+off_d
            const int e2 = e - 400;
            const int jj = e2 / 9, d = e2 % 9;
            const int ey = d / 3 - 1, ex = d % 3 - 1;
            valsL[jj][d] = -sw[ey + 1][jj + 1 + ex] * sc[ey + 1][jj + 1 + ex][8 - d];
        } else if (e < 688) {                // U: -w_t[j] M_t[j,k]
            const int e2 = e - 544;
            const int jj = e2 / 9, qi = e2 % 9;
            valsU[jj][qi] = -sw[1][jj + 1] * sc[1][jj + 1][qi];
        }
    }
    __syncthreads();

    // phase 2: 48 coalesced nontemporal float4 stores per thread
    const int q   = tid;                 // quad index within a 1024-float row
    const int ky  = q >> 3, kx0 = (q & 7) * 4;
    const int ddy = ky - jy;             // same for all 16 j's in this block
    f32x4* const outq = (f32x4*)out;
    const size_t matD = ((size_t)(b * 3 + 0) * NT + t) << 18;   // quads per matrix
    const size_t matL = ((size_t)(b * 3 + 1) * NT + t) << 18;
    const int ut = (t >= 1) ? (t - 1) : 7;
    const size_t matU = ((size_t)(b * 3 + 2) * NT + ut) << 18;
    const bool inD  = (ddy >= -2 && ddy <= 2);
    const bool inLU = (ddy >= -1 && ddy <= 1);

    #pragma unroll 4
    for (int jj = 0; jj < 16; ++jj) {
        const int jx = jx0 + jj;
        const int j  = jy * NX + jx;
        const size_t rq = ((size_t)j << 8) + q;
        float4 vD = make_float4(0.f, 0.f, 0.f, 0.f);
        float4 vL = make_float4(0.f, 0.f, 0.f, 0.f);
        float4 vU = make_float4(0.f, 0.f, 0.f, 0.f);
        if (inD) {
            float* vp = &vD.x;
            const float* wrow = &valsD[jj][(ddy + 2) * 5 + 2];
            #pragma unroll
            for (int qq = 0; qq < 4; ++qq) {
                const int ddx = kx0 + qq - jx;
                if (ddx >= -2 && ddx <= 2) vp[qq] = wrow[ddx];
            }
        }
        if (inLU) {
            if (t > 0) {
                float* vp = &vL.x;
                const float* wrow = &valsL[jj][(ddy + 1) * 3 + 1];
                #pragma unroll
                for (int qq = 0; qq < 4; ++qq) {
                    const int ddx = kx0 + qq - jx;
                    if (ddx >= -1 && ddx <= 1) vp[qq] = wrow[ddx];
                }
            }
            if (t >= 1) {
                float* vp = &vU.x;
                const float* wrow = &valsU[jj][(ddy + 1) * 3 + 1];
                #pragma unroll
                for (int qq = 0; qq < 4; ++qq) {
                    const int ddx = kx0 + qq - jx;
                    if (ddx >= -1 && ddx <= 1) vp[qq] = wrow[ddx];
                }
            }
        }
        nt_store(outq + matD + rq, vD);
        nt_store(outq + matL + rq, vL);
        nt_store(outq + matU + rq, vU);
    }
}

extern "C" void kernel_launch(void* const* d_in, const int* in_sizes, int n_in,
                              void* d_out, int out_size, void* d_ws, size_t ws_size,
                              hipStream_t stream) {
    (void)n_in; (void)d_ws; (void)ws_size; (void)out_size;
    const float* kap = (const float*)d_in[0];  // [n_b,1,N,NT]
    const float* m   = (const float*)d_in[1];  // [n_b,2,N,NT]
    const float* H   = (const float*)d_in[2];  // [n_b,2,2,N,NT]
    const float* tau = (const float*)d_in[3];  // [n_b,1,N,NT]
    float* out = (float*)d_out;                // [n_b,3,NT,N,N]

    const int n_b = in_sizes[0] / (NN * NT);
    const int grid = n_b * NT * NY * 2;        // one block per (b,t,jy,half-row)
    spde_fused<<<grid, 256, 0, stream>>>(kap, m, H, tau, out);
}

// Round 5
// 190.963 us; speedup vs baseline: 1.1145x; 1.1145x over previous
//
#include <hip/hip_runtime.h>

#define NT 8
#define NY 32
#define NX 32
#define NN 1024  // NY*NX

typedef __attribute__((ext_vector_type(4))) float f32x4;

// Stencil coefficients of M = I + A for one node. c[(ry+1)*3+(rx+1)] is the
// coefficient toward target offset (ry,rx); zeroed when the TARGET node falls
// off-grid (matches reference `valid` masking on the column node).
__device__ __forceinline__ void node_coefs(const float* __restrict__ kap,
                                           const float* __restrict__ m,
                                           const float* __restrict__ H,
                                           const float* __restrict__ tau,
                                           int b, int node, int tc,
                                           int iy, int ix,
                                           float* c /*[9]*/, float& w) {
    const int base = node * NT + tc;                 // [.., node, t] layout, last dim NT
    const float kp  = kap[(b * NN) * NT + base];
    const float m1  = m[((b * 2 + 0) * NN) * NT + base];
    const float m2  = m[((b * 2 + 1) * NN) * NT + base];
    const float h11 = H[((b * 4 + 0) * NN) * NT + base];
    const float h12 = H[((b * 4 + 1) * NN) * NT + base];
    const float h22 = H[((b * 4 + 3) * NN) * NT + base];
    const float tv  = tau[(b * NN) * NT + base];
    w = 1.0f / (tv * tv);

    const float cxy = 0.5f * h12;
    const bool ym = iy > 0, yp = iy < NY - 1;
    const bool xm = ix > 0, xp = ix < NX - 1;

    c[4] = 1.0f + kp * kp + 2.0f * h11 + 2.0f * h22;
    c[0] = (ym && xm) ? -cxy               : 0.0f;
    c[1] =  ym        ? (-h22 - 0.5f * m2) : 0.0f;
    c[2] = (ym && xp) ?  cxy               : 0.0f;
    c[3] =  xm        ? (-h11 - 0.5f * m1) : 0.0f;
    c[5] =  xp        ? (-h11 + 0.5f * m1) : 0.0f;
    c[6] = (yp && xm) ?  cxy               : 0.0f;
    c[7] =  yp        ? (-h22 + 0.5f * m2) : 0.0f;
    c[8] = (yp && xp) ? -cxy               : 0.0f;
}

// Scatter over a pre-zeroed output. ONE block per (b, t, jy): computes the
// stencil coefs of grid rows jy-1..jy+1 once, the band values for all 32 j's
// of the row, then streams the nonzero bands out:
//   D[t]   rows j=jy*32+jj : 5 consecutive 128B ky-segments (640B contiguous)
//   L[t]   rows           : 3 consecutive segments (384B), t>=1
//   U[t-1] rows           : 3 consecutive segments (384B), t>=1
// Consecutive lanes write consecutive quads within a span; spans of
// consecutive jj are 4KB apart inside one 128KB region -> streaming stores.
// L[0] and U[7] remain memset-zero.
__global__ __launch_bounds__(256) void spde_scatter_row(const float* __restrict__ kap,
                                                        const float* __restrict__ m,
                                                        const float* __restrict__ H,
                                                        const float* __restrict__ tau,
                                                        float* __restrict__ out) {
    __shared__ float sc[3][34][9];   // coefs of node (jy-1+ly, lx-1); x-halo zeroed
    __shared__ float sw[3][34];      // w_t at those nodes (0 off-grid)
    __shared__ float valsD[32][25];
    __shared__ float valsL[32][9];
    __shared__ float valsU[32][9];

    const int gb  = blockIdx.x;          // (b*NT + t)*NY + jy
    const int jy  = gb & 31;
    const int t   = (gb >> 5) & 7;
    const int b   = gb >> 8;
    const int tid = threadIdx.x;

    // phase A: coefs for the 3x34 (with x-halo) neighborhood nodes at time t
    if (tid < 102) {
        const int ly = tid / 34, lx = tid % 34;
        const int iy = jy + ly - 1, ix = lx - 1;
        float c[9];
        float w = 0.0f;
        if (iy >= 0 && iy < NY && ix >= 0 && ix < NX) {
            node_coefs(kap, m, H, tau, b, iy * NX + ix, t, iy, ix, c, w);
        } else {
            #pragma unroll
            for (int q = 0; q < 9; ++q) c[q] = 0.0f;
        }
        #pragma unroll
        for (int q = 0; q < 9; ++q) sc[ly][lx][q] = c[q];
        sw[ly][lx] = w;
    }
    __syncthreads();

    // phase B: 1376 band values (32 j x (25 D + 9 L + 9 U)) over 256 threads
    #pragma unroll
    for (int pass = 0; pass < 6; ++pass) {
        const int e = tid + pass * 256;
        if (e < 800) {                        // D: sum_i w[i] M[i,j] M[i,k]
            const int jj = e / 25, l = e % 25;
            const int dy = l / 5 - 2, dx = l % 5 - 2;
            float acc = 0.0f;
            #pragma unroll
            for (int d = 0; d < 9; ++d) {     // rows i = j + off_d
                const int ey = d / 3 - 1, ex = d % 3 - 1;
                const int r2y = dy - ey, r2x = dx - ex;
                if (r2y >= -1 && r2y <= 1 && r2x >= -1 && r2x <= 1) {
                    const float* ci = sc[ey + 1][jj + 1 + ex];
                    acc += sw[ey + 1][jj + 1 + ex] * ci[8 - d]
                                                   * ci[(r2y + 1) * 3 + (r2x + 1)];
                }
            }
            if (l == 12 && t < NT - 1) {      // diagonal: + w_{t+1}[j]
                const int j = jy * NX + jj;
                const float tv = tau[((size_t)b * NN + j) * NT + (t + 1)];
                acc += 1.0f / (tv * tv);
            }
            valsD[jj][l] = acc;
        } else if (e < 1088) {                // L: -w_t[k] M_t[k,j], k=j+off_d
            const int e2 = e - 800;
            const int jj = e2 / 9, d = e2 % 9;
            const int ey = d / 3 - 1, ex = d % 3 - 1;
            valsL[jj][d] = -sw[ey + 1][jj + 1 + ex] * sc[ey + 1][jj + 1 + ex][8 - d];
        } else if (e < 1376) {                // U: -w_t[j] M_t[j,k]
            const int e2 = e - 1088;
            const int jj = e2 / 9, qi = e2 % 9;
            valsU[jj][qi] = -sw[1][jj + 1] * sc[1][jj + 1][qi];
        }
    }
    __syncthreads();

    // phase C: streaming band stores
    f32x4* const outq = (f32x4*)out;
    const size_t matD = ((size_t)(b * 3 + 0) * NT + t) << 18;   // quads per matrix
    const int rowbase = jy * NX;                                 // j = rowbase + jj

    // D: 32 jj x 5 segments x 8 quads = 1280 quads, 5 per thread
    #pragma unroll
    for (int pass = 0; pass < 5; ++pass) {
        const int idx = tid + pass * 256;
        const int jj = idx / 40, r = idx % 40;
        const int s = r >> 3, q = r & 7;     // segment (ky = jy-2+s), quad in segment
        const int ky = jy - 2 + s;
        if (ky >= 0 && ky < NY) {
            f32x4 v = {0.f, 0.f, 0.f, 0.f};
            #pragma unroll
            for (int cq = 0; cq < 4; ++cq) {
                const int ddx = q * 4 + cq - jj;          // kx - jx
                if (ddx >= -2 && ddx <= 2) v[cq] = valsD[jj][s * 5 + (ddx + 2)];
            }
            outq[matD + ((size_t)(rowbase + jj) << 8) + ky * 8 + q] = v;
        }
    }

    if (t >= 1) {
        const size_t matL = ((size_t)(b * 3 + 1) * NT + t) << 18;
        const size_t matU = ((size_t)(b * 3 + 2) * NT + (t - 1)) << 18;
        // L: 32 jj x 3 segments x 8 quads = 768 quads, 3 per thread
        #pragma unroll
        for (int pass = 0; pass < 3; ++pass) {
            const int idx = tid + pass * 256;
            const int jj = idx / 24, r = idx % 24;
            const int s = r >> 3, q = r & 7;
            const int ky = jy - 1 + s;
            if (ky >= 0 && ky < NY) {
                f32x4 v = {0.f, 0.f, 0.f, 0.f};
                #pragma unroll
                for (int cq = 0; cq < 4; ++cq) {
                    const int ddx = q * 4 + cq - jj;
                    if (ddx >= -1 && ddx <= 1) v[cq] = valsL[jj][s * 3 + (ddx + 1)];
                }
                outq[matL + ((size_t)(rowbase + jj) << 8) + ky * 8 + q] = v;
            }
        }
        // U: same geometry as L
        #pragma unroll
        for (int pass = 0; pass < 3; ++pass) {
            const int idx = tid + pass * 256;
            const int jj = idx / 24, r = idx % 24;
            const int s = r >> 3, q = r & 7;
            const int ky = jy - 1 + s;
            if (ky >= 0 && ky < NY) {
                f32x4 v = {0.f, 0.f, 0.f, 0.f};
                #pragma unroll
                for (int cq = 0; cq < 4; ++cq) {
                    const int ddx = q * 4 + cq - jj;
                    if (ddx >= -1 && ddx <= 1) v[cq] = valsU[jj][s * 3 + (ddx + 1)];
                }
                outq[matU + ((size_t)(rowbase + jj) << 8) + ky * 8 + q] = v;
            }
        }
    }
}

extern "C" void kernel_launch(void* const* d_in, const int* in_sizes, int n_in,
                              void* d_out, int out_size, void* d_ws, size_t ws_size,
                              hipStream_t stream) {
    (void)n_in; (void)d_ws; (void)ws_size;
    const float* kap = (const float*)d_in[0];  // [n_b,1,N,NT]
    const float* m   = (const float*)d_in[1];  // [n_b,2,N,NT]
    const float* H   = (const float*)d_in[2];  // [n_b,2,2,N,NT]
    const float* tau = (const float*)d_in[3];  // [n_b,1,N,NT]
    float* out = (float*)d_out;                // [n_b,3,NT,N,N]

    const int n_b = in_sizes[0] / (NN * NT);

    // Phase 1: zero the whole output via the vendor fill path (~6.3 TB/s measured).
    hipMemsetAsync(d_out, 0, (size_t)out_size, stream);

    // Phase 2: streaming band scatter, one fat block per (b, t, jy).
    const int grid = n_b * NT * NY;
    spde_scatter_row<<<grid, 256, 0, stream>>>(kap, m, H, tau, out);
}